// Round 5
// baseline (178.787 us; speedup 1.0000x reference)
//
#include <hip/hip_runtime.h>
#include <hip/hip_bf16.h>
#include <stdint.h>

// Problem constants: B=4, CIN=COUT=256, H=W=64, 3x3, pad=1, stride=1, dil=1
#define KDIM 2304   // CIN * 9, GEMM K

typedef __bf16 bf16_t;
typedef bf16_t bf16x8 __attribute__((ext_vector_type(8)));
typedef float f32x4 __attribute__((ext_vector_type(4)));
typedef float f32x2 __attribute__((ext_vector_type(2)));

__device__ __forceinline__ float b2f_lo(uint32_t u) {
  union { uint32_t i; float f; } c; c.i = u << 16; return c.f;
}
__device__ __forceinline__ float b2f_hi(uint32_t u) {
  union { uint32_t i; float f; } c; c.i = u & 0xffff0000u; return c.f;
}
// pack 2 floats -> 2 bf16 (RNE), a in low half
__device__ __forceinline__ uint32_t pk_bf16(float a, float b) {
  __hip_bfloat162 h = __float22bfloat162_rn(make_float2(a, b));
  union { __hip_bfloat162 h; uint32_t u; } c; c.h = h; return c.u;
}

// async 16B global -> LDS; lds dst must be wave-uniform, HW adds lane*16
__device__ __forceinline__ void g2lds16(const uint16_t* g, uint16_t* l) {
  __builtin_amdgcn_global_load_lds((const __attribute__((address_space(1))) void*)g,
                                   (__attribute__((address_space(3))) void*)l,
                                   16, 0, 0);
}

// ---------------- kernel 1 (merged prep):
// blocks [0,2048): x [4][256][64][64] f32 -> xt [4][64][64][256] bf16
//   block = (b, cgrp of 32 ch, sgrp of 64 spatial)
// blocks [2048,2304): weight [256][256][3][3] f32 -> wt [cout][tap*256+cin] bf16
//   block = one cout row
__global__ __launch_bounds__(256) void k_prep(const float* __restrict__ x,
                                              uint16_t* __restrict__ xt,
                                              const float* __restrict__ w,
                                              uint16_t* __restrict__ wt) {
  int tid = threadIdx.x;
  if (blockIdx.x < 2048) {
    __shared__ float tile[32][65];
    int b = blockIdx.x >> 9;
    int cgrp = (blockIdx.x >> 6) & 7;
    int sgrp = blockIdx.x & 63;
    int c0 = cgrp << 5, s0 = sgrp << 6;
    // load 32 ch x 64 sp as float4 (512 float4, 2 per thread)
#pragma unroll
    for (int it = 0; it < 2; ++it) {
      int f = tid + it * 256;
      int r = f >> 4, col = (f & 15) << 2;
      float4 v = *(const float4*)&x[((size_t)(b * 256 + c0 + r)) * 4096 + s0 + col];
      tile[r][col + 0] = v.x;
      tile[r][col + 1] = v.y;
      tile[r][col + 2] = v.z;
      tile[r][col + 3] = v.w;
    }
    __syncthreads();
    // write: thread (sp = tid>>2, cg = tid&3) packs 8 ch -> uint4
    int sp = tid >> 2, cg = tid & 3;
    uint4 o;
    o.x = pk_bf16(tile[cg * 8 + 0][sp], tile[cg * 8 + 1][sp]);
    o.y = pk_bf16(tile[cg * 8 + 2][sp], tile[cg * 8 + 3][sp]);
    o.z = pk_bf16(tile[cg * 8 + 4][sp], tile[cg * 8 + 5][sp]);
    o.w = pk_bf16(tile[cg * 8 + 6][sp], tile[cg * 8 + 7][sp]);
    *(uint4*)&xt[((size_t)b * 4096 + s0 + sp) * 256 + c0 + cg * 8] = o;
  } else {
    __shared__ float wl[2304];
    int cout = blockIdx.x - 2048;
    const float* wrow = w + (size_t)cout * 2304;
    for (int i = tid; i < 576; i += 256)
      *(float4*)&wl[i * 4] = *(const float4*)&wrow[i * 4];
    __syncthreads();
    // thread c: 9 taps of channel c -> wt[cout][tap*256 + c]
    uint16_t* wdst = wt + (size_t)cout * KDIM + tid;
#pragma unroll
    for (int t = 0; t < 9; ++t)
      wdst[t * 256] = (uint16_t)(pk_bf16(wl[tid * 9 + t], 0.f) & 0xffffu);
  }
}

// ---------------- kernel 2: FUSED deform-im2col + GEMM
// C[m][n] = sum_k wt[m][k] * cols(n,k), cols built per half-tap in LDS.
// Block: 256 thr = 4 waves (2x2), wave-tile 64m x 64n, block tile 128m x 128n.
// Grid dim3(128, 2) = 256 blocks = 1/CU. One block = 2 output rows (b, ho0, ho0+1).
// K loop: 9 taps x 2 half-taps (BK=128 = 4 sub-tiles of 32 ch).
__global__ __launch_bounds__(256, 1) void k_fused(const uint16_t* __restrict__ xt,
                                                  const uint16_t* __restrict__ wt,
                                                  const float* __restrict__ off,
                                                  const float* __restrict__ msk,
                                                  const float* __restrict__ bias,
                                                  float* __restrict__ out) {
  __shared__ __align__(16) uint16_t As[4][128][32];  // 32 KB, [kchunk][m][kk]
  __shared__ __align__(16) uint16_t Bs[4][128][32];  // 32 KB, [kchunk][n][kk]
  __shared__ float s_off[18 * 128];                  // 9 KB
  __shared__ float s_msk[9 * 128];                   // 4.5 KB

  int tid = threadIdx.x;
  int b = blockIdx.x >> 5;
  int hobase = (blockIdx.x & 31) << 1;
  int n0 = b * 4096 + hobase * 64;
  int m0 = blockIdx.y << 7;

  // stage offsets/masks for the 128 positions (2 rows): contiguous 128-float runs
  const float* offb = off + (size_t)b * 18 * 4096 + hobase * 64;
  for (int i = tid; i < 18 * 128; i += 256)
    s_off[i] = offb[(size_t)(i >> 7) * 4096 + (i & 127)];
  const float* mskb = msk + (size_t)b * 9 * 4096 + hobase * 64;
  for (int i = tid; i < 9 * 128; i += 256)
    s_msk[i] = mskb[(size_t)(i >> 7) * 4096 + (i & 127)];
  __syncthreads();

  int lane = tid & 63, wv = tid >> 6;
  int wm = wv >> 1, wn = wv & 1;
  int q = lane >> 4, r = lane & 15;

  f32x4 acc[4][4];
#pragma unroll
  for (int i = 0; i < 4; ++i)
#pragma unroll
    for (int j = 0; j < 4; ++j) acc[i][j] = f32x4{0.f, 0.f, 0.f, 0.f};

  // A staging: wave wv fills sub-tile As[wv]; per DMA j: rows j*16..j*16+15
  // lane l -> row j*16 + (l>>2), k-chunk (l&3)*8
  const uint16_t* aptr = wt + (size_t)(m0 + (lane >> 2)) * KDIM + wv * 32 + (lane & 3) * 8;

  // B staging: thread -> position p (0..127), half (0..1) = 64 channels
  int p = tid >> 1, half = tid & 1;
  const uint16_t* xtb = xt + (size_t)b * 4096 * 256 + half * 64;
  int ho_p = hobase + (p >> 6);
  int wo_p = p & 63;

  for (int tap = 0; tap < 9; ++tap) {
    int kh = tap / 3, kw = tap - kh * 3;
    float dy = s_off[(2 * tap) * 128 + p];
    float dx = s_off[(2 * tap + 1) * 128 + p];
    float mm = s_msk[tap * 128 + p];
    float sy = (float)(ho_p - 1 + kh) + dy;
    float sx = (float)(wo_p - 1 + kw) + dx;
    float fy = floorf(sy), fx = floorf(sx);
    int y0 = (int)fy, x0 = (int)fx;
    float wy = sy - fy, wx = sx - fx;
    float cw[4];
    const uint16_t* cp[4];
#pragma unroll
    for (int cy = 0; cy < 2; ++cy) {
#pragma unroll
      for (int cx = 0; cx < 2; ++cx) {
        int y = y0 + cy, xx = x0 + cx;
        float wgt = (cy ? wy : 1.f - wy) * (cx ? wx : 1.f - wx) * mm;
        bool v = ((unsigned)y < 64u) && ((unsigned)xx < 64u);
        wgt = v ? wgt : 0.f;
        int yc = min(max(y, 0), 63), xc = min(max(xx, 0), 63);
        cw[cy * 2 + cx] = wgt;
        cp[cy * 2 + cx] = xtb + ((yc << 6) + xc) * 256;
      }
    }
    const uint16_t* atap = aptr + tap * 256;
#pragma unroll
    for (int ht = 0; ht < 2; ++ht) {
      // ---- A: 8 async DMAs fill As[wv] (128 rows x 32 ch)
#pragma unroll
      for (int j = 0; j < 8; ++j)
        g2lds16(atap + ht * 128 + (size_t)j * 16 * KDIM, &As[wv][j * 16][0]);
      // ---- B: gather 4 corners x 64 ch, blend, pack, write 8x b128
      int choff = ht * 128;
      f32x2 facc[32];
#pragma unroll
      for (int u = 0; u < 32; ++u) facc[u] = f32x2{0.f, 0.f};
#pragma unroll
      for (int c = 0; c < 4; ++c) {
        const uint4* src = (const uint4*)(cp[c] + choff);
        uint4 d[8];
#pragma unroll
        for (int u = 0; u < 8; ++u) d[u] = src[u];
        f32x2 wc = {cw[c], cw[c]};
#pragma unroll
        for (int u = 0; u < 8; ++u) {
          facc[u * 4 + 0] += wc * f32x2{b2f_lo(d[u].x), b2f_hi(d[u].x)};
          facc[u * 4 + 1] += wc * f32x2{b2f_lo(d[u].y), b2f_hi(d[u].y)};
          facc[u * 4 + 2] += wc * f32x2{b2f_lo(d[u].z), b2f_hi(d[u].z)};
          facc[u * 4 + 3] += wc * f32x2{b2f_lo(d[u].w), b2f_hi(d[u].w)};
        }
      }
#pragma unroll
      for (int cc = 0; cc < 8; ++cc) {
        uint4 o;
        o.x = pk_bf16(facc[cc * 4 + 0].x, facc[cc * 4 + 0].y);
        o.y = pk_bf16(facc[cc * 4 + 1].x, facc[cc * 4 + 1].y);
        o.z = pk_bf16(facc[cc * 4 + 2].x, facc[cc * 4 + 2].y);
        o.w = pk_bf16(facc[cc * 4 + 3].x, facc[cc * 4 + 3].y);
        int st = half * 2 + (cc >> 2);
        *(uint4*)&Bs[st][p][(cc & 3) * 8] = o;
      }
      __syncthreads();
      // ---- MFMA: 4 sub-tiles x 16 = 64 MFMA per wave
#pragma unroll
      for (int st = 0; st < 4; ++st) {
        bf16x8 af[4], bf[4];
#pragma unroll
        for (int mi = 0; mi < 4; ++mi)
          af[mi] = *(const bf16x8*)&As[st][wm * 64 + mi * 16 + r][q * 8];
#pragma unroll
        for (int ni = 0; ni < 4; ++ni)
          bf[ni] = *(const bf16x8*)&Bs[st][wn * 64 + ni * 16 + r][q * 8];
#pragma unroll
        for (int mi = 0; mi < 4; ++mi)
#pragma unroll
          for (int ni = 0; ni < 4; ++ni)
            acc[mi][ni] = __builtin_amdgcn_mfma_f32_16x16x32_bf16(af[mi], bf[ni], acc[mi][ni], 0, 0, 0);
      }
      __syncthreads();
    }
  }

  // epilogue: C/D layout col = lane&15 (n), row = q*4 + j (m)
#pragma unroll
  for (int mi = 0; mi < 4; ++mi) {
#pragma unroll
    for (int j = 0; j < 4; ++j) {
      int m = m0 + wm * 64 + mi * 16 + q * 4 + j;
      float bv = bias[m];
#pragma unroll
      for (int ni = 0; ni < 4; ++ni) {
        int n = n0 + wn * 64 + ni * 16 + r;
        int bb = n >> 12, pp = n & 4095;
        out[((size_t)(bb * 256 + m)) * 4096 + pp] = acc[mi][ni][j] + bv;
      }
    }
  }
}

extern "C" void kernel_launch(void* const* d_in, const int* in_sizes, int n_in,
                              void* d_out, int out_size, void* d_ws, size_t ws_size,
                              hipStream_t stream) {
  (void)in_sizes; (void)n_in; (void)out_size; (void)ws_size;
  const float* x      = (const float*)d_in[0];  // [4][256][64][64]
  const float* offset = (const float*)d_in[1];  // [4][18][64][64]
  const float* mask   = (const float*)d_in[2];  // [4][9][64][64]
  const float* weight = (const float*)d_in[3];  // [256][256][3][3]
  const float* bias   = (const float*)d_in[4];  // [256]
  float* out = (float*)d_out;                   // [4][256][64][64]

  uint8_t* ws = (uint8_t*)d_ws;
  uint16_t* xt = (uint16_t*)ws;                 // 8,388,608 B : NHWC bf16
  uint16_t* wt = (uint16_t*)(ws + 8388608);     // 1,179,648 B : [cout][tap*256+cin]

  k_prep<<<dim3(2304), 256, 0, stream>>>(x, xt, weight, wt);
  k_fused<<<dim3(128, 2), 256, 0, stream>>>(xt, wt, offset, mask, bias, out);
}

// Round 6
// 132.187 us; speedup vs baseline: 1.3525x; 1.3525x over previous
//
#include <hip/hip_runtime.h>
#include <hip/hip_bf16.h>
#include <stdint.h>

// Problem constants: B=4, CIN=COUT=256, H=W=64, 3x3, pad=1, stride=1, dil=1
#define KDIM 2304   // CIN * 9, GEMM K

typedef __bf16 bf16_t;
typedef bf16_t bf16x8 __attribute__((ext_vector_type(8)));
typedef float f32x4 __attribute__((ext_vector_type(4)));
typedef float f32x2 __attribute__((ext_vector_type(2)));

__device__ __forceinline__ float b2f_lo(uint32_t u) {
  union { uint32_t i; float f; } c; c.i = u << 16; return c.f;
}
__device__ __forceinline__ float b2f_hi(uint32_t u) {
  union { uint32_t i; float f; } c; c.i = u & 0xffff0000u; return c.f;
}
__device__ __forceinline__ uint32_t pk_bf16(float a, float b) {
  __hip_bfloat162 h = __float22bfloat162_rn(make_float2(a, b));
  union { __hip_bfloat162 h; uint32_t u; } c; c.h = h; return c.u;
}

// async 16B global -> LDS; lds dst wave-uniform, HW adds lane*16
__device__ __forceinline__ void g2lds16(const uint16_t* g, uint16_t* l) {
  __builtin_amdgcn_global_load_lds((const __attribute__((address_space(1))) void*)g,
                                   (__attribute__((address_space(3))) void*)l,
                                   16, 0, 0);
}

// ---------------- merged prep kernel
// blocks [0,2048): x [4][256][64][64] f32 -> xt [4][64][64][256] bf16
// blocks [2048,2304): weight [256][256][3][3] f32 -> wt [cout][tap*256+cin] bf16
__global__ __launch_bounds__(256) void k_prep(const float* __restrict__ x,
                                              uint16_t* __restrict__ xt,
                                              const float* __restrict__ w,
                                              uint16_t* __restrict__ wt) {
  int tid = threadIdx.x;
  if (blockIdx.x < 2048) {
    __shared__ float tile[32][65];
    int b = blockIdx.x >> 9;
    int cgrp = (blockIdx.x >> 6) & 7;
    int sgrp = blockIdx.x & 63;
    int c0 = cgrp << 5, s0 = sgrp << 6;
#pragma unroll
    for (int it = 0; it < 2; ++it) {
      int f = tid + it * 256;
      int rr = f >> 4, col = (f & 15) << 2;
      float4 v = *(const float4*)&x[((size_t)(b * 256 + c0 + rr)) * 4096 + s0 + col];
      tile[rr][col + 0] = v.x;
      tile[rr][col + 1] = v.y;
      tile[rr][col + 2] = v.z;
      tile[rr][col + 3] = v.w;
    }
    __syncthreads();
    int sp = tid >> 2, cg = tid & 3;
    uint4 o;
    o.x = pk_bf16(tile[cg * 8 + 0][sp], tile[cg * 8 + 1][sp]);
    o.y = pk_bf16(tile[cg * 8 + 2][sp], tile[cg * 8 + 3][sp]);
    o.z = pk_bf16(tile[cg * 8 + 4][sp], tile[cg * 8 + 5][sp]);
    o.w = pk_bf16(tile[cg * 8 + 6][sp], tile[cg * 8 + 7][sp]);
    *(uint4*)&xt[((size_t)b * 4096 + s0 + sp) * 256 + c0 + cg * 8] = o;
  } else {
    __shared__ float wl[2304];
    int cout = blockIdx.x - 2048;
    const float* wrow = w + (size_t)cout * 2304;
    for (int i = tid; i < 576; i += 256)
      *(float4*)&wl[i * 4] = *(const float4*)&wrow[i * 4];
    __syncthreads();
    uint16_t* wdst = wt + (size_t)cout * KDIM + tid;
#pragma unroll
    for (int t = 0; t < 9; ++t)
      wdst[t * 256] = (uint16_t)(pk_bf16(wl[tid * 9 + t], 0.f) & 0xffffu);
  }
}

// per-thread bilinear corner setup for one tap
__device__ __forceinline__ void mk_corners(int tap, int p, int ho,
                                           const float* s_off, const float* s_msk,
                                           const uint16_t* xtb,
                                           float cw[4], const uint16_t* cp[4]) {
  int kh = tap / 3, kw = tap - kh * 3;
  float dy = s_off[(2 * tap) * 64 + p];
  float dx = s_off[(2 * tap + 1) * 64 + p];
  float mm = s_msk[tap * 64 + p];
  float sy = (float)(ho - 1 + kh) + dy;
  float sx = (float)(p - 1 + kw) + dx;
  float fy = floorf(sy), fx = floorf(sx);
  int y0 = (int)fy, x0 = (int)fx;
  float wy = sy - fy, wx = sx - fx;
#pragma unroll
  for (int cy = 0; cy < 2; ++cy) {
#pragma unroll
    for (int cx = 0; cx < 2; ++cx) {
      int y = y0 + cy, xx = x0 + cx;
      float wgt = (cy ? wy : 1.f - wy) * (cx ? wx : 1.f - wx) * mm;
      bool v = ((unsigned)y < 64u) && ((unsigned)xx < 64u);
      wgt = v ? wgt : 0.f;
      int yc = min(max(y, 0), 63), xc = min(max(xx, 0), 63);
      cw[cy * 2 + cx] = wgt;
      cp[cy * 2 + cx] = xtb + ((yc << 6) + xc) * 256;
    }
  }
}

// blend 4 corners (8 ch each) -> packed bf16x8
__device__ __forceinline__ uint4 blend4(const uint4 d[4], const float cw[4]) {
  f32x2 f0 = {0.f, 0.f}, f1 = {0.f, 0.f}, f2 = {0.f, 0.f}, f3 = {0.f, 0.f};
#pragma unroll
  for (int c = 0; c < 4; ++c) {
    f32x2 wc = {cw[c], cw[c]};
    f0 += wc * f32x2{b2f_lo(d[c].x), b2f_hi(d[c].x)};
    f1 += wc * f32x2{b2f_lo(d[c].y), b2f_hi(d[c].y)};
    f2 += wc * f32x2{b2f_lo(d[c].z), b2f_hi(d[c].z)};
    f3 += wc * f32x2{b2f_lo(d[c].w), b2f_hi(d[c].w)};
  }
  uint4 o;
  o.x = pk_bf16(f0.x, f0.y);
  o.y = pk_bf16(f1.x, f1.y);
  o.z = pk_bf16(f2.x, f2.y);
  o.w = pk_bf16(f3.x, f3.y);
  return o;
}

// ---------------- FUSED deform-im2col + GEMM, software-pipelined
// Block: 512 thr = 8 waves, BM=256 (all cout), BN=64 (one (b,ho) row), BK=64.
// Grid 256 blocks = 1/CU. 36 K-iters (9 taps x 4), double-buffered As/Bs,
// one barrier per iter; next-iter gathers + A-DMAs issued right after the
// barrier so they complete during the current iter's MFMA phase.
__global__ __launch_bounds__(512, 2) void k_fused(const uint16_t* __restrict__ xt,
                                                  const uint16_t* __restrict__ wt,
                                                  const float* __restrict__ off,
                                                  const float* __restrict__ msk,
                                                  const float* __restrict__ bias,
                                                  float* __restrict__ out) {
  __shared__ __align__(16) uint16_t As[2][2][256][32];  // 64 KB [buf][kh][m][kk]
  __shared__ __align__(16) uint16_t Bs[2][2][64][32];   // 16 KB [buf][kh][n][kk]
  __shared__ float s_off[18 * 64];
  __shared__ float s_msk[9 * 64];

  int tid = threadIdx.x;
  int b = blockIdx.x >> 6, ho = blockIdx.x & 63;

  const float* offb = off + (size_t)b * 18 * 4096 + ho * 64;
  for (int i = tid; i < 18 * 64; i += 512)
    s_off[i] = offb[(size_t)(i >> 6) * 4096 + (i & 63)];
  const float* mskb = msk + (size_t)b * 9 * 4096 + ho * 64;
  for (int i = tid; i < 9 * 64; i += 512)
    s_msk[i] = mskb[(size_t)(i >> 6) * 4096 + (i & 63)];

  int lane = tid & 63, wv = tid >> 6;
  int wm = wv >> 1, wn = wv & 1;           // 4 m-groups x 2 n-groups, 64x32 tiles
  int q = lane >> 4, r = lane & 15;

  // B gather mapping: position p (0..63), channel chunk cg*8 within 64-ch window
  int p = tid >> 3, cg = tid & 7;
  const uint16_t* xtb = xt + (size_t)b * 4096 * 256 + cg * 8;
  int bsub = cg >> 2, bcol = (cg & 3) * 8;

  // A DMA mapping: wave wv covers sub kh=wv&1, rows (wv>>1)*64 + j*16
  int asub = wv & 1, arow0 = (wv >> 1) * 64;
  const uint16_t* abase = wt + (size_t)(arow0 + (lane >> 2)) * KDIM + asub * 32 + (lane & 3) * 8;

  f32x4 acc[4][2];
#pragma unroll
  for (int i = 0; i < 4; ++i)
#pragma unroll
    for (int j = 0; j < 2; ++j) acc[i][j] = f32x4{0.f, 0.f, 0.f, 0.f};

  __syncthreads();  // off/msk staged

  float cw[4];
  const uint16_t* cp[4];

  // ---- prologue: prepare iter 0 into buf 0
  mk_corners(0, p, ho, s_off, s_msk, xtb, cw, cp);
  {
    uint4 d0[4];
#pragma unroll
    for (int c = 0; c < 4; ++c) d0[c] = *(const uint4*)(cp[c]);
#pragma unroll
    for (int j = 0; j < 4; ++j)
      g2lds16(abase + (size_t)(j * 16) * KDIM, &As[0][asub][arow0 + j * 16][0]);
    uint4 o = blend4(d0, cw);
    *(uint4*)&Bs[0][bsub][p][bcol] = o;
  }

  for (int i = 0; i < 36; ++i) {
    int cur = i & 1;
    __syncthreads();   // publish buf[cur] (drains A-DMA vmcnt + B ds_writes)
    uint4 dn[4];
    if (i != 35) {
      int nx = i + 1;
      if ((nx & 3) == 0) mk_corners(nx >> 2, p, ho, s_off, s_msk, xtb, cw, cp);
      int ofs = (nx & 3) * 64;
#pragma unroll
      for (int c = 0; c < 4; ++c) dn[c] = *(const uint4*)(cp[c] + ofs);
      int ofsK = (nx >> 2) * 256 + (nx & 3) * 64;
      int nb = nx & 1;
#pragma unroll
      for (int j = 0; j < 4; ++j)
        g2lds16(abase + ofsK + (size_t)(j * 16) * KDIM, &As[nb][asub][arow0 + j * 16][0]);
    }
    // ---- consume buf[cur]: 16 MFMA per wave
    bf16x8 af[4][2], bfr[2][2];
#pragma unroll
    for (int kh = 0; kh < 2; ++kh) {
#pragma unroll
      for (int mi = 0; mi < 4; ++mi)
        af[mi][kh] = *(const bf16x8*)&As[cur][kh][wm * 64 + mi * 16 + r][q * 8];
#pragma unroll
      for (int ni = 0; ni < 2; ++ni)
        bfr[ni][kh] = *(const bf16x8*)&Bs[cur][kh][wn * 32 + ni * 16 + r][q * 8];
    }
#pragma unroll
    for (int kh = 0; kh < 2; ++kh)
#pragma unroll
      for (int mi = 0; mi < 4; ++mi)
#pragma unroll
        for (int ni = 0; ni < 2; ++ni)
          acc[mi][ni] = __builtin_amdgcn_mfma_f32_16x16x32_bf16(af[mi][kh], bfr[ni][kh], acc[mi][ni], 0, 0, 0);
    if (i != 35) {
      uint4 o = blend4(dn, cw);
      *(uint4*)&Bs[(i + 1) & 1][bsub][p][bcol] = o;
    }
  }

  // epilogue: C/D layout col = lane&15 (n), row = q*4 + j (m)
#pragma unroll
  for (int mi = 0; mi < 4; ++mi) {
#pragma unroll
    for (int j = 0; j < 4; ++j) {
      int m = wm * 64 + mi * 16 + q * 4 + j;
      float bv = bias[m];
#pragma unroll
      for (int ni = 0; ni < 2; ++ni) {
        int wo = wn * 32 + ni * 16 + r;
        out[((size_t)(b * 256 + m)) * 4096 + ho * 64 + wo] = acc[mi][ni][j] + bv;
      }
    }
  }
}

extern "C" void kernel_launch(void* const* d_in, const int* in_sizes, int n_in,
                              void* d_out, int out_size, void* d_ws, size_t ws_size,
                              hipStream_t stream) {
  (void)in_sizes; (void)n_in; (void)out_size; (void)ws_size;
  const float* x      = (const float*)d_in[0];  // [4][256][64][64]
  const float* offset = (const float*)d_in[1];  // [4][18][64][64]
  const float* mask   = (const float*)d_in[2];  // [4][9][64][64]
  const float* weight = (const float*)d_in[3];  // [256][256][3][3]
  const float* bias   = (const float*)d_in[4];  // [256]
  float* out = (float*)d_out;                   // [4][256][64][64]

  uint8_t* ws = (uint8_t*)d_ws;
  uint16_t* xt = (uint16_t*)ws;                 // 8,388,608 B : NHWC bf16
  uint16_t* wt = (uint16_t*)(ws + 8388608);     // 1,179,648 B : [cout][tap*256+cin]

  k_prep<<<dim3(2304), 256, 0, stream>>>(x, xt, weight, wt);
  k_fused<<<dim3(256), 512, 0, stream>>>(xt, wt, offset, mask, bias, out);
}